// Round 13
// baseline (10073.357 us; speedup 1.0000x reference)
//
#include <hip/hip_runtime.h>
#include <stdint.h>

// ---- problem constants ----
constexpr int HD   = 512;
constexpr int TS   = 256;
constexpr int NB   = 64;
constexpr int MBR  = 128;
constexpr int SLAB = MBR * HD;   // 65536 elements per h-slab

typedef __attribute__((ext_vector_type(8))) short bf16x8;
typedef __attribute__((ext_vector_type(4))) float f32x4;

__device__ __forceinline__ unsigned short f2bf(float f){
  union { float f; unsigned u; } v; v.f = f;
  unsigned r = v.u + 0x7fffu + ((v.u >> 16) & 1u);
  return (unsigned short)(r >> 16);
}
__device__ __forceinline__ float fsig(float x){ return 1.f / (1.f + __expf(-x)); }
__device__ __forceinline__ float ftanh(float x){ return 1.f - 2.f / (__expf(2.f * x) + 1.f); }
__device__ __forceinline__ void vdrain(){ asm volatile("s_waitcnt vmcnt(0)" ::: "memory"); }

// device-scope (memory-side, placement-independent) flag ops — R12-proven
__device__ __forceinline__ int ld_flag_sc1(const int* p){
  int v;
  asm volatile("global_load_dword %0, %1, off sc0 sc1\n\ts_waitcnt vmcnt(0)"
               : "=v"(v) : "v"(p) : "memory");
  return v;
}
__device__ __forceinline__ void st_sc1_b32(void* p, int v){
  asm volatile("global_store_dword %0, %1, off sc0 sc1" :: "v"(p), "v"(v) : "memory");
}

// 16 x 16B sc1 loads (one A-row K-half, 256B/lane). R12-proven pattern.
__device__ __forceinline__ void ld16_sc1(const void* p, f32x4* r){
  asm volatile(
    "global_load_dwordx4 %0,  %16, off sc0 sc1\n\t"
    "global_load_dwordx4 %1,  %16, off offset:64 sc0 sc1\n\t"
    "global_load_dwordx4 %2,  %16, off offset:128 sc0 sc1\n\t"
    "global_load_dwordx4 %3,  %16, off offset:192 sc0 sc1\n\t"
    "global_load_dwordx4 %4,  %16, off offset:256 sc0 sc1\n\t"
    "global_load_dwordx4 %5,  %16, off offset:320 sc0 sc1\n\t"
    "global_load_dwordx4 %6,  %16, off offset:384 sc0 sc1\n\t"
    "global_load_dwordx4 %7,  %16, off offset:448 sc0 sc1\n\t"
    "global_load_dwordx4 %8,  %16, off offset:512 sc0 sc1\n\t"
    "global_load_dwordx4 %9,  %16, off offset:576 sc0 sc1\n\t"
    "global_load_dwordx4 %10, %16, off offset:640 sc0 sc1\n\t"
    "global_load_dwordx4 %11, %16, off offset:704 sc0 sc1\n\t"
    "global_load_dwordx4 %12, %16, off offset:768 sc0 sc1\n\t"
    "global_load_dwordx4 %13, %16, off offset:832 sc0 sc1\n\t"
    "global_load_dwordx4 %14, %16, off offset:896 sc0 sc1\n\t"
    "global_load_dwordx4 %15, %16, off offset:960 sc0 sc1\n\t"
    "s_waitcnt vmcnt(0)"
    : "=&v"(r[0]), "=&v"(r[1]), "=&v"(r[2]), "=&v"(r[3]),
      "=&v"(r[4]), "=&v"(r[5]), "=&v"(r[6]), "=&v"(r[7]),
      "=&v"(r[8]), "=&v"(r[9]), "=&v"(r[10]), "=&v"(r[11]),
      "=&v"(r[12]), "=&v"(r[13]), "=&v"(r[14]), "=&v"(r[15])
    : "v"(p) : "memory");
}
__device__ __forceinline__ bf16x8 pack8(float4 a, float4 b){
  bf16x8 w;
  w[0]=(short)f2bf(a.x); w[1]=(short)f2bf(a.y); w[2]=(short)f2bf(a.z); w[3]=(short)f2bf(a.w);
  w[4]=(short)f2bf(b.x); w[5]=(short)f2bf(b.y); w[6]=(short)f2bf(b.z); w[7]=(short)f2bf(b.w);
  return w;
}

// Persistent pipelined 2-layer LSTM — placement-independent, redundancy-free.
// 64 WGs x 512 thr, 1 WG/CU, 128 KB LDS combined weights.
// Role from blockIdx.x ONLY: layer = wg>>5, slice = wg&31 (16 units).
// Each WG computes ALL 128 batch rows x its 16 units x 4 gates.
// Wave wv = m-frag mi in [0,8) (16 rows each, DISTINCT per wave -> no duplicate
// A reads); each wave computes all 4 col-frags (64 gate-cols).
// All h/flag traffic device-scope sc1 (L3): correct for ANY WG placement.
// h0x full-depth [256]: L0 free-runs, no circular waits. Polls capped (~2M).
__global__ __launch_bounds__(512, 1)
void lstm_persist(const float* __restrict__ text,
                  const float* __restrict__ Wih0, const float* __restrict__ Whh0,
                  const float* __restrict__ bih0, const float* __restrict__ bhh0,
                  const float* __restrict__ Wih1, const float* __restrict__ Whh1,
                  const float* __restrict__ bih1, const float* __restrict__ bhh1,
                  unsigned short* __restrict__ h0x,   // [256][128][512] full depth
                  unsigned short* __restrict__ h1r,   // [4][128][512] ring
                  float* __restrict__ H1f,            // [128][512] final h1 fp32
                  int* __restrict__ F)                // [2][256][32] flags
{
  extern __shared__ unsigned short Blds[];   // 64 cols x 1024 k, swizzled, 128 KB
  __shared__ int s_abort;

  const int wg    = blockIdx.x;
  const int layer = wg >> 5;
  const int slice = wg & 31;
  const int u0    = slice * 16;
  const int tid   = threadIdx.x;
  const int wv    = tid >> 6;     // = mi, m-frag index (16 rows)
  const int l     = tid & 63;
  const int lj    = l & 15;
  const int lk    = l >> 4;
  const int mi    = wv;

  if (tid == 0) s_abort = 0;

  int* F0 = F;                    // layer-0 flags [256][32]
  int* F1 = F + TS * 32;          // layer-1 flags [256][32]

  // ---- one-time: combined weight slice -> LDS (f32 -> bf16, swizzled) ----
  const float* Wihl = layer ? Wih1 : Wih0;
  const float* Whhl = layer ? Whh1 : Whh0;
  for (int it = tid; it < 64 * 128; it += 512){
    int c = it >> 7, kg = it & 127;
    int unit = u0 + ((c >> 4) << 2) + ((c & 15) >> 2);
    int gate = c & 3;
    const float* s = (kg < 64) ? (Wihl + (size_t)(gate * HD + unit) * HD + kg * 8)
                               : (Whhl + (size_t)(gate * HD + unit) * HD + (kg - 64) * 8);
    *(bf16x8*)((char*)Blds + c * 2048 + ((kg ^ (c & 7)) << 4)) =
        pack8(((const float4*)s)[0], ((const float4*)s)[1]);
  }

  const int mygate = lj & 3;
  const int usub   = lj >> 2;                 // 0..3 within a col-frag
  float bgv[4];
  #pragma unroll
  for (int cf = 0; cf < 4; ++cf){
    int unit = u0 + cf * 4 + usub;
    bgv[cf] = (layer ? bih1 : bih0)[mygate * HD + unit]
            + (layer ? bhh1 : bhh0)[mygate * HD + unit];
  }
  const int arow = mi * 16 + lj;              // this lane's A row (0..127)
  const int aoff = arow * HD + lk * 8;        // A element offset (row,k)
  const int swz  = lj & 7;

  float cst[4][4] = {};                       // [cf][r] cell state
  __syncthreads();   // weights staged, s_abort visible

  auto ldsB = [&](int cf, int kg)->bf16x8 {
    return *(const bf16x8*)((const char*)Blds + (cf * 16 + lj) * 2048 + ((kg ^ swz) << 4));
  };
  // wave-0 poll of 32 flags (lanes 0..31 and 32..63 mirror). sc1. Liveness cap.
  auto pollwait = [&](const int* base){
    if (*(volatile int*)&s_abort) return;
    const int* fp = base + (l & 31);
    int it = 0;
    for (;;){
      int v = ld_flag_sc1(fp);
      if (__all(v != 0)) break;
      if (++it > 2000000){ s_abort = 1; break; }
      __builtin_amdgcn_s_sleep(1);
    }
  };
  // one K-half of the gate GEMM: 16 loads (done by caller) -> 64 MFMA
  auto mfmaHalf = [&](const f32x4* raw, int gb, f32x4* acc){
    #pragma unroll
    for (int kk = 0; kk < 16; ++kk){
      bf16x8 a = __builtin_bit_cast(bf16x8, raw[kk]);
      #pragma unroll
      for (int cf = 0; cf < 4; ++cf)
        acc[cf] = __builtin_amdgcn_mfma_f32_16x16x32_bf16(
                    a, ldsB(cf, gb + kk * 4 + lk), acc[cf], 0, 0, 0);
    }
  };
  // cell update; packed sc1 h store (dword = 2 units); optional fp32 final write
  auto cellstore = [&](const f32x4* aP, const f32x4* aQ,
                       unsigned short* __restrict__ hslab, bool wrF){
    #pragma unroll
    for (int cf = 0; cf < 4; ++cf){
      #pragma unroll
      for (int r = 0; r < 4; ++r){
        float v  = aP[cf][r] + aQ[cf][r] + bgv[cf];
        float v1 = __shfl_xor(v, 1);
        float v2 = __shfl_xor(v, 2);
        float v3 = __shfl_xor(v, 3);
        auto pick = [&](int m)->float {
          return m == 0 ? v : (m == 1 ? v1 : (m == 2 ? v2 : v3));
        };
        float gi = pick(mygate);
        float gf = pick(mygate ^ 1);
        float gg = pick(mygate ^ 2);
        float go = pick(mygate ^ 3);
        float i_ = fsig(gi);
        float f_ = fsig(gf);
        float g_ = ftanh(gg);
        float o_ = fsig(go);
        float c  = f_ * cst[cf][r] + i_ * g_;
        cst[cf][r] = c;
        float h  = o_ * ftanh(c);
        int row  = mi * 16 + lk * 4 + r;
        int unit = u0 + cf * 4 + usub;
        int hb   = (int)f2bf(h);
        int pb   = __shfl_xor(hb, 4);        // partner: unit+1, same gate
        if ((lj & 7) == 0)                   // lj in {0,8}: even units, gate 0
          st_sc1_b32((char*)hslab + ((size_t)row * HD + unit) * 2,
                     (hb & 0xffff) | (pb << 16));
        if (wrF && mygate == 0)
          H1f[(size_t)row * HD + unit] = h;
      }
    }
  };
  // L0 input projection: text f32 direct (plain cached, read-only), cvt in-flight
  auto preX = [&](int t, f32x4* acc){
    int b   = arow & 63;
    int ts2 = (arow < 64) ? t : (TS - 1 - t);
    const float* src = text + ((size_t)b * TS + ts2) * HD + lk * 8;
    #pragma unroll
    for (int cf = 0; cf < 4; ++cf) acc[cf] = (f32x4){0.f, 0.f, 0.f, 0.f};
    #pragma unroll
    for (int kk = 0; kk < 16; ++kk){
      const float* s = src + kk * 32;
      bf16x8 a = pack8(((const float4*)s)[0], ((const float4*)s)[1]);
      #pragma unroll
      for (int cf = 0; cf < 4; ++cf)
        acc[cf] = __builtin_amdgcn_mfma_f32_16x16x32_bf16(
                    a, ldsB(cf, kk * 4 + lk), acc[cf], 0, 0, 0);
    }
  };

  f32x4 accPre[4], accPost[4];

  if (layer == 0){
    // ================= layer 0: free-running (no backpressure ever) ==========
    preX(0, accPre);
    for (int t = 0; t < TS; ++t){
      #pragma unroll
      for (int cf = 0; cf < 4; ++cf) accPost[cf] = (f32x4){0.f, 0.f, 0.f, 0.f};
      if (t > 0){
        if (wv == 0) pollwait(F0 + (t - 1) * 32);
        __syncthreads();
        f32x4 raw[16];
        ld16_sc1(h0x + (size_t)(t - 1) * SLAB + aoff, raw);
        mfmaHalf(raw, 64, accPost);
      }
      cellstore(accPre, accPost, h0x + (size_t)t * SLAB, false);
      vdrain();                 // sc1 stores acked at coherence point
      __syncthreads();
      if (tid == 0) st_sc1_b32(F0 + t * 32 + slice, 1);
      if (t + 1 < TS) preX(t + 1, accPre);   // off critical path
    }
  } else {
    // ================= layer 1: chases L0 ====================================
    if (wv == 0) pollwait(F0 + 0);
    __syncthreads();
    {
      f32x4 raw[16];
      ld16_sc1(h0x + aoff, raw);
      #pragma unroll
      for (int cf = 0; cf < 4; ++cf) accPre[cf] = (f32x4){0.f, 0.f, 0.f, 0.f};
      mfmaHalf(raw, 0, accPre);
    }
    for (int t = 0; t < TS; ++t){
      #pragma unroll
      for (int cf = 0; cf < 4; ++cf) accPost[cf] = (f32x4){0.f, 0.f, 0.f, 0.f};
      if (t > 0){
        if (wv == 0) pollwait(F1 + (t - 1) * 32);   // peers done t-1
        __syncthreads();
        f32x4 raw[16];
        ld16_sc1(h1r + (size_t)((t - 1) & 3) * SLAB + aoff, raw);
        mfmaHalf(raw, 64, accPost);
      }
      cellstore(accPre, accPost, h1r + (size_t)(t & 3) * SLAB, t == TS - 1);
      vdrain();
      __syncthreads();
      if (tid == 0) st_sc1_b32(F1 + t * 32 + slice, 1);
      if (t + 1 < TS){
        // prefetch+project h0x[t+1]; overlaps peers' detect of our release.
        // L0 never depends on L1 -> F0[t+1] always eventually set (no deadlock).
        if (wv == 0) pollwait(F0 + (t + 1) * 32);
        __syncthreads();
        f32x4 raw[16];
        ld16_sc1(h0x + (size_t)(t + 1) * SLAB + aoff, raw);
        #pragma unroll
        for (int cf = 0; cf < 4; ++cf) accPre[cf] = (f32x4){0.f, 0.f, 0.f, 0.f};
        mfmaHalf(raw, 0, accPre);
      }
    }
  }
}

// out[b] = dot(h1_fwd[b], Wlin[0:512]) + dot(h1_rev[b], Wlin[512:1024]) + blin
__global__ void final_linear(const float* __restrict__ H1f, const float* __restrict__ Wlin,
                             const float* __restrict__ blin, float* __restrict__ out){
  int b = blockIdx.x, l = threadIdx.x;
  float s = 0.f;
  for (int j = l; j < HD; j += 64) s += H1f[(size_t)b * HD + j]        * Wlin[j];
  for (int j = l; j < HD; j += 64) s += H1f[(size_t)(NB + b) * HD + j] * Wlin[HD + j];
  #pragma unroll
  for (int off = 32; off; off >>= 1) s += __shfl_down(s, off);
  if (l == 0) out[b] = s + blin[0];
}

extern "C" void kernel_launch(void* const* d_in, const int* in_sizes, int n_in,
                              void* d_out, int out_size, void* d_ws, size_t ws_size,
                              hipStream_t stream)
{
  const float* text = (const float*)d_in[0];
  const float* Wih0 = (const float*)d_in[1];
  const float* Whh0 = (const float*)d_in[2];
  const float* bih0 = (const float*)d_in[3];
  const float* bhh0 = (const float*)d_in[4];
  const float* Wih1 = (const float*)d_in[5];
  const float* Whh1 = (const float*)d_in[6];
  const float* bih1 = (const float*)d_in[7];
  const float* bhh1 = (const float*)d_in[8];
  const float* Wlin = (const float*)d_in[9];
  const float* blin = (const float*)d_in[10];

  // ---- ws layout (~33 MiB) ----
  uint8_t* p = (uint8_t*)d_ws;
  unsigned short* h0x = (unsigned short*)p; p += (size_t)TS * SLAB * 2;     // 32 MiB
  unsigned short* h1r = (unsigned short*)p; p += (size_t)4 * SLAB * 2;      // 512 KiB
  float* H1f          = (float*)p;          p += (size_t)SLAB * 4;          // 256 KiB
  int* F              = (int*)p;            p += (size_t)2 * TS * 32 * 4;   // 64 KiB

  // deterministic init: flags zero at kernel start
  hipMemsetAsync(F, 0, (size_t)2 * TS * 32 * 4, stream);

  hipFuncSetAttribute((const void*)lstm_persist,
                      hipFuncAttributeMaxDynamicSharedMemorySize, 131072);

  const float* A0 = text;
  const float *A1 = Wih0, *A2 = Whh0, *A3 = bih0, *A4 = bhh0;
  const float *A5 = Wih1, *A6 = Whh1, *A7 = bih1, *A8 = bhh1;
  unsigned short* B0 = h0x; unsigned short* B1 = h1r;
  float* B2 = H1f; int* B3 = F;
  void* args[] = {(void*)&A0,
                  (void*)&A1, (void*)&A2, (void*)&A3, (void*)&A4,
                  (void*)&A5, (void*)&A6, (void*)&A7, (void*)&A8,
                  (void*)&B0, (void*)&B1, (void*)&B2, (void*)&B3};
  hipLaunchCooperativeKernel((void*)lstm_persist, dim3(64), dim3(512),
                             args, 131072, stream);

  final_linear<<<NB, 64, 0, stream>>>(H1f, Wlin, blin, (float*)d_out);
}

// Round 14
// 3750.700 us; speedup vs baseline: 2.6857x; 2.6857x over previous
//
#include <hip/hip_runtime.h>
#include <stdint.h>

// ---- problem constants ----
constexpr int HD   = 512;
constexpr int TS   = 256;
constexpr int NB   = 64;
constexpr int MBR  = 128;
constexpr int SLAB = MBR * HD;   // 65536 elements per h-slab

typedef __attribute__((ext_vector_type(8))) short bf16x8;
typedef __attribute__((ext_vector_type(4))) float f32x4;

__device__ __forceinline__ unsigned short f2bf(float f){
  union { float f; unsigned u; } v; v.f = f;
  unsigned r = v.u + 0x7fffu + ((v.u >> 16) & 1u);
  return (unsigned short)(r >> 16);
}
__device__ __forceinline__ float fsig(float x){ return 1.f / (1.f + __expf(-x)); }
__device__ __forceinline__ float ftanh(float x){ return 1.f - 2.f / (__expf(2.f * x) + 1.f); }
__device__ __forceinline__ void vdrain(){ asm volatile("s_waitcnt vmcnt(0)" ::: "memory"); }

// device-scope (memory-side, placement-independent) flag ops — R12-proven
__device__ __forceinline__ int ld_flag_sc1(const int* p){
  int v;
  asm volatile("global_load_dword %0, %1, off sc0 sc1\n\ts_waitcnt vmcnt(0)"
               : "=v"(v) : "v"(p) : "memory");
  return v;
}
__device__ __forceinline__ void st_sc1_b32(void* p, int v){
  asm volatile("global_store_dword %0, %1, off sc0 sc1" :: "v"(p), "v"(v) : "memory");
}

// 16 x 16B loads (one A-row K-half, 256B/lane), single trailing waitcnt.
// sc1 variant (uncached, memory-side) — R12-proven.
// sc0 variant (L2-cacheable, L1-bypass) — R6-proven; safe on write-once
// buffers after the kernel-entry acquire fence (see below).
#define LD16_DEF(NAME, FLAGS)                                                   \
__device__ __forceinline__ void NAME(const void* p, f32x4* r){                  \
  asm volatile(                                                                 \
    "global_load_dwordx4 %0,  %16, off " FLAGS "\n\t"                           \
    "global_load_dwordx4 %1,  %16, off offset:64 " FLAGS "\n\t"                 \
    "global_load_dwordx4 %2,  %16, off offset:128 " FLAGS "\n\t"                \
    "global_load_dwordx4 %3,  %16, off offset:192 " FLAGS "\n\t"                \
    "global_load_dwordx4 %4,  %16, off offset:256 " FLAGS "\n\t"                \
    "global_load_dwordx4 %5,  %16, off offset:320 " FLAGS "\n\t"                \
    "global_load_dwordx4 %6,  %16, off offset:384 " FLAGS "\n\t"                \
    "global_load_dwordx4 %7,  %16, off offset:448 " FLAGS "\n\t"                \
    "global_load_dwordx4 %8,  %16, off offset:512 " FLAGS "\n\t"                \
    "global_load_dwordx4 %9,  %16, off offset:576 " FLAGS "\n\t"                \
    "global_load_dwordx4 %10, %16, off offset:640 " FLAGS "\n\t"                \
    "global_load_dwordx4 %11, %16, off offset:704 " FLAGS "\n\t"                \
    "global_load_dwordx4 %12, %16, off offset:768 " FLAGS "\n\t"                \
    "global_load_dwordx4 %13, %16, off offset:832 " FLAGS "\n\t"                \
    "global_load_dwordx4 %14, %16, off offset:896 " FLAGS "\n\t"                \
    "global_load_dwordx4 %15, %16, off offset:960 " FLAGS "\n\t"                \
    "s_waitcnt vmcnt(0)"                                                        \
    : "=&v"(r[0]), "=&v"(r[1]), "=&v"(r[2]), "=&v"(r[3]),                       \
      "=&v"(r[4]), "=&v"(r[5]), "=&v"(r[6]), "=&v"(r[7]),                       \
      "=&v"(r[8]), "=&v"(r[9]), "=&v"(r[10]), "=&v"(r[11]),                     \
      "=&v"(r[12]), "=&v"(r[13]), "=&v"(r[14]), "=&v"(r[15])                    \
    : "v"(p) : "memory");                                                       \
}
LD16_DEF(ld16_sc1, "sc0 sc1")
LD16_DEF(ld16_c,   "sc0")

__device__ __forceinline__ bf16x8 pack8(float4 a, float4 b){
  bf16x8 w;
  w[0]=(short)f2bf(a.x); w[1]=(short)f2bf(a.y); w[2]=(short)f2bf(a.z); w[3]=(short)f2bf(a.w);
  w[4]=(short)f2bf(b.x); w[5]=(short)f2bf(b.y); w[6]=(short)f2bf(b.z); w[7]=(short)f2bf(b.w);
  return w;
}

// Persistent pipelined 2-layer LSTM — placement-independent (R12 protocol).
// 256 WGs x 512 thr, 1 WG/CU, 128 KB LDS combined weights.
// Role from blockIdx.x ONLY: layer = wg>>7, grp = (wg>>5)&3, slice = wg&31.
// Producers: sc1 packed h stores -> vmcnt -> barrier -> sc1 flag (R12-proven).
// Consumers: sc1 flag poll, then h reads via sc0 L2-CACHED loads.
//   Safety of cached reads: (1) one acquire(agent) fence at kernel entry
//   invalidates stale/poisoned L2 lines; (2) h buffers are WRITE-ONCE per
//   call (no ring reuse when h1full=1) so no address is ever re-written;
//   (3) reads are flag-gated, so an L2 miss fetches the producer's
//   memory-side value; a replay-cached line holds the identical value.
// h0x full-depth [256]: L0 free-runs, no circular waits. Polls capped (~2M).
__global__ __launch_bounds__(512, 1)
void lstm_persist(const float* __restrict__ text,
                  const float* __restrict__ Wih0, const float* __restrict__ Whh0,
                  const float* __restrict__ bih0, const float* __restrict__ bhh0,
                  const float* __restrict__ Wih1, const float* __restrict__ Whh1,
                  const float* __restrict__ bih1, const float* __restrict__ bhh1,
                  unsigned short* __restrict__ h0x,   // [256][128][512] full depth
                  unsigned short* __restrict__ h1x,   // [256] full OR [4] ring
                  float* __restrict__ H1f,            // [128][512] final h1 fp32
                  int* __restrict__ F,                // [2][4][256][32] flags
                  int h1full)                         // 1: h1x write-once (cached reads)
{
  extern __shared__ unsigned short Blds[];   // 64 cols x 1024 k, swizzled, 128 KB
  __shared__ int s_abort;

  const int wg    = blockIdx.x;
  const int layer = wg >> 7;
  const int grp   = (wg >> 5) & 3;
  const int slice = wg & 31;
  const int m0    = grp * 32;
  const int u0    = slice * 16;
  const int tid   = threadIdx.x;
  const int wv    = tid >> 6;
  const int l     = tid & 63;
  const int lj    = l & 15;
  const int lk    = l >> 4;
  const int wgrp  = wv & 3;
  const int mi    = wv >> 2;

  if (tid == 0) s_abort = 0;
  // one-time L2 invalidate: drop any stale/poisoned lines so subsequent
  // sc0-cached reads of write-once buffers are always coherent.
  __builtin_amdgcn_fence(__ATOMIC_ACQUIRE, "agent");

  int* F0g = F + (0 + grp) * (TS * 32);        // layer-0 flags, this group
  int* F1g = F + (4 + grp) * (TS * 32);        // layer-1 flags, this group

  // ---- one-time: combined weight slice -> LDS (f32 -> bf16, swizzled) ----
  const float* Wihl = layer ? Wih1 : Wih0;
  const float* Whhl = layer ? Whh1 : Whh0;
  for (int it = tid; it < 64 * 128; it += 512){
    int c = it >> 7, kg = it & 127;
    int unit = u0 + ((c >> 4) << 2) + ((c & 15) >> 2);
    int gate = c & 3;
    const float* s = (kg < 64) ? (Wihl + (size_t)(gate * HD + unit) * HD + kg * 8)
                               : (Whhl + (size_t)(gate * HD + unit) * HD + (kg - 64) * 8);
    *(bf16x8*)((char*)Blds + c * 2048 + ((kg ^ (c & 7)) << 4)) =
        pack8(((const float4*)s)[0], ((const float4*)s)[1]);
  }

  const int myunit = u0 + (wgrp << 2) + (lj >> 2);
  const int mygate = lj & 3;
  const float bgv  = (layer ? bih1 : bih0)[mygate * HD + myunit]
                   + (layer ? bhh1 : bhh0)[mygate * HD + myunit];
  const int aoff   = (m0 + mi * 16 + lj) * HD + lk * 8;   // A element offset (row,k)
  const int cboff  = (wgrp * 16 + lj) * 2048;             // B col byte base in LDS
  const int swz    = lj & 7;

  float cst[4] = {0.f, 0.f, 0.f, 0.f};
  __syncthreads();   // weights staged, s_abort visible

  auto ldsB = [&](int kg)->bf16x8 {
    return *(const bf16x8*)((const char*)Blds + cboff + ((kg ^ swz) << 4));
  };
  // wave-0 poll of 32 flags (lanes 0..31 and 32..63 mirror). sc1. Liveness cap.
  auto pollwait = [&](const int* pA, const int* pB){
    if (*(volatile int*)&s_abort) return;
    const int* fp = (l < 32) ? (pA + l) : (pB + (l - 32));
    int it = 0;
    for (;;){
      int v = ld_flag_sc1(fp);
      if (__all(v != 0)) break;
      if (++it > 2000000){ s_abort = 1; break; }
      __builtin_amdgcn_s_sleep(1);
    }
  };
  // cell update; packed sc1 h store (dword = 2 units); optional fp32 final write
  auto cellstore = [&](const f32x4& aP, const f32x4& aQ,
                       unsigned short* __restrict__ hslab, bool wrF){
    #pragma unroll
    for (int r = 0; r < 4; ++r){
      float v  = aP[r] + aQ[r] + bgv;
      float v1 = __shfl_xor(v, 1);
      float v2 = __shfl_xor(v, 2);
      float v3 = __shfl_xor(v, 3);
      auto pick = [&](int m)->float {
        return m == 0 ? v : (m == 1 ? v1 : (m == 2 ? v2 : v3));
      };
      float gi = pick(mygate);
      float gf = pick(mygate ^ 1);
      float gg = pick(mygate ^ 2);
      float go = pick(mygate ^ 3);
      float i_ = fsig(gi);
      float f_ = fsig(gf);
      float g_ = ftanh(gg);
      float o_ = fsig(go);
      float c  = f_ * cst[r] + i_ * g_;
      cst[r] = c;
      float h  = o_ * ftanh(c);
      int row  = m0 + mi * 16 + lk * 4 + r;
      int hb   = (int)f2bf(h);
      int pb   = __shfl_xor(hb, 4);          // partner unit (myunit+1)
      if ((lj & 7) == 0)                     // lanes lj in {0,8}: even units
        st_sc1_b32((char*)hslab + ((size_t)row * HD + myunit) * 2,
                   (hb & 0xffff) | (pb << 16));
      if (wrF && mygate == 0)
        H1f[(size_t)row * HD + myunit] = h;
    }
  };
  // L0 input projection: text f32 direct (plain cached, read-only), cvt in-flight
  auto preX = [&](int t, f32x4& acc){
    int ar  = m0 + mi * 16 + lj;
    int b   = ar & 63;
    int ts2 = (ar < 64) ? t : (TS - 1 - t);
    const float* src = text + ((size_t)b * TS + ts2) * HD + lk * 8;
    acc = (f32x4){0.f, 0.f, 0.f, 0.f};
    #pragma unroll
    for (int kk = 0; kk < 16; ++kk){
      const float* s = src + kk * 32;
      bf16x8 a = pack8(((const float4*)s)[0], ((const float4*)s)[1]);
      acc = __builtin_amdgcn_mfma_f32_16x16x32_bf16(a, ldsB(kk * 4 + lk), acc, 0, 0, 0);
    }
  };

  if (layer == 0){
    // ================= layer 0: free-running (no backpressure ever) ==========
    f32x4 accPre;
    preX(0, accPre);
    for (int t = 0; t < TS; ++t){
      if (t > 0){
        if (wv == 0) pollwait(F0g + (t - 1) * 32, F0g + (t - 1) * 32);
        __syncthreads();
      }
      f32x4 accPost = {0.f, 0.f, 0.f, 0.f};
      if (t > 0){
        f32x4 raw[16];
        ld16_c(h0x + (size_t)(t - 1) * SLAB + aoff, raw);   // L2-cached read
        #pragma unroll
        for (int kk = 0; kk < 16; ++kk)
          accPost = __builtin_amdgcn_mfma_f32_16x16x32_bf16(
                      __builtin_bit_cast(bf16x8, raw[kk]), ldsB(64 + kk * 4 + lk),
                      accPost, 0, 0, 0);
      }
      cellstore(accPre, accPost, h0x + (size_t)t * SLAB, false);
      vdrain();                 // sc1 stores acked at coherence point
      __syncthreads();
      if (tid == 0) st_sc1_b32(F0g + t * 32 + slice, 1);
      if (t + 1 < TS) preX(t + 1, accPre);   // off critical path
    }
  } else {
    // ================= layer 1: chases L0 (merged poll, no circular wait) ====
    for (int t = 0; t < TS; ++t){
      if (wv == 0){
        const int* pA = (t > 0) ? (F1g + (t - 1) * 32) : (F0g + 0);
        pollwait(pA, F0g + t * 32);          // peers done t-1  ∥  L0 done t
      }
      __syncthreads();
      f32x4 rawI[16], rawR[16];
      ld16_c(h0x + (size_t)t * SLAB + aoff, rawI);          // L2-cached read
      if (t > 0){
        if (h1full) ld16_c  (h1x + (size_t)(t - 1) * SLAB + aoff, rawR);
        else        ld16_sc1(h1x + (size_t)((t - 1) & 3) * SLAB + aoff, rawR);
      }
      f32x4 accPre  = {0.f, 0.f, 0.f, 0.f};
      f32x4 accPost = {0.f, 0.f, 0.f, 0.f};
      #pragma unroll
      for (int kk = 0; kk < 16; ++kk)
        accPre = __builtin_amdgcn_mfma_f32_16x16x32_bf16(
                   __builtin_bit_cast(bf16x8, rawI[kk]), ldsB(kk * 4 + lk),
                   accPre, 0, 0, 0);
      if (t > 0){
        #pragma unroll
        for (int kk = 0; kk < 16; ++kk)
          accPost = __builtin_amdgcn_mfma_f32_16x16x32_bf16(
                      __builtin_bit_cast(bf16x8, rawR[kk]), ldsB(64 + kk * 4 + lk),
                      accPost, 0, 0, 0);
      }
      unsigned short* hout = h1full ? (h1x + (size_t)t * SLAB)
                                    : (h1x + (size_t)(t & 3) * SLAB);
      cellstore(accPre, accPost, hout, t == TS - 1);
      vdrain();
      __syncthreads();
      if (tid == 0) st_sc1_b32(F1g + t * 32 + slice, 1);
    }
  }
}

// out[b] = dot(h1_fwd[b], Wlin[0:512]) + dot(h1_rev[b], Wlin[512:1024]) + blin
__global__ void final_linear(const float* __restrict__ H1f, const float* __restrict__ Wlin,
                             const float* __restrict__ blin, float* __restrict__ out){
  int b = blockIdx.x, l = threadIdx.x;
  float s = 0.f;
  for (int j = l; j < HD; j += 64) s += H1f[(size_t)b * HD + j]        * Wlin[j];
  for (int j = l; j < HD; j += 64) s += H1f[(size_t)(NB + b) * HD + j] * Wlin[HD + j];
  #pragma unroll
  for (int off = 32; off; off >>= 1) s += __shfl_down(s, off);
  if (l == 0) out[b] = s + blin[0];
}

extern "C" void kernel_launch(void* const* d_in, const int* in_sizes, int n_in,
                              void* d_out, int out_size, void* d_ws, size_t ws_size,
                              hipStream_t stream)
{
  const float* text = (const float*)d_in[0];
  const float* Wih0 = (const float*)d_in[1];
  const float* Whh0 = (const float*)d_in[2];
  const float* bih0 = (const float*)d_in[3];
  const float* bhh0 = (const float*)d_in[4];
  const float* Wih1 = (const float*)d_in[5];
  const float* Whh1 = (const float*)d_in[6];
  const float* bih1 = (const float*)d_in[7];
  const float* bhh1 = (const float*)d_in[8];
  const float* Wlin = (const float*)d_in[9];
  const float* blin = (const float*)d_in[10];

  // ---- ws layout: h0x[256] always; h1x full-depth if ws_size allows ----
  const size_t H0X   = (size_t)TS * SLAB * 2;    // 32 MiB
  const size_t H1FULL= (size_t)TS * SLAB * 2;    // 32 MiB
  const size_t H1RING= (size_t)4 * SLAB * 2;     // 512 KiB
  const size_t H1FB  = (size_t)SLAB * 4;         // 256 KiB
  const size_t FB    = (size_t)8 * TS * 32 * 4;  // 256 KiB
  int h1full = (ws_size >= H0X + H1FULL + H1FB + FB + 65536) ? 1 : 0;

  uint8_t* p = (uint8_t*)d_ws;
  unsigned short* h0x = (unsigned short*)p; p += H0X;
  unsigned short* h1x = (unsigned short*)p; p += (h1full ? H1FULL : H1RING);
  float* H1f          = (float*)p;          p += H1FB;
  int* F              = (int*)p;            p += FB;

  // deterministic init: flags zero at kernel start
  hipMemsetAsync(F, 0, FB, stream);

  hipFuncSetAttribute((const void*)lstm_persist,
                      hipFuncAttributeMaxDynamicSharedMemorySize, 131072);

  const float* A0 = text;
  const float *A1 = Wih0, *A2 = Whh0, *A3 = bih0, *A4 = bhh0;
  const float *A5 = Wih1, *A6 = Whh1, *A7 = bih1, *A8 = bhh1;
  unsigned short* B0 = h0x; unsigned short* B1 = h1x;
  float* B2 = H1f; int* B3 = F; int B4 = h1full;
  void* args[] = {(void*)&A0,
                  (void*)&A1, (void*)&A2, (void*)&A3, (void*)&A4,
                  (void*)&A5, (void*)&A6, (void*)&A7, (void*)&A8,
                  (void*)&B0, (void*)&B1, (void*)&B2, (void*)&B3, (void*)&B4};
  hipLaunchCooperativeKernel((void*)lstm_persist, dim3(256), dim3(512),
                             args, 131072, stream);

  final_linear<<<NB, 64, 0, stream>>>(H1f, Wlin, blin, (float*)d_out);
}